// Round 14
// baseline (55.006 us; speedup 1.0000x reference)
//
#include <hip/hip_runtime.h>
#include <stdint.h>

// ROI max-pool (aspect-preserving "OCR" variant) — DMA-staged, v11.
// feats: (B=4, C=128, H=64, W=512) fp32
// rois:  (N, 5) fp32 = [batch, x1, y1, x2, y2] image coords, spatial scale 0.25
// out:   (N, C, PH=8, PW=32) fp32
//
// R10 was at its register-limited MLP roofline (~128 B in flight/wave ->
// 3.1 TB/s reads). This version stages via global_load_lds DMA (in-flight
// bytes live in the vmcnt queue, not VGPRs): per item (n, ph, 4-channel
// group) one wave DMAs the raw window (nh<=5 rows x wwid<=111 cols x 4
// planes, 4B/lane, exec-trimmed to wwid) into LDS, waits vmcnt(0), then
// computes each bin max directly from LDS (nh x 5 masked unroll, nw<=5).
// 2 independent 1-wave items per 128-thr block (no barrier; per-wave
// vmcnt). LDS 2x10KB -> 8 blocks = 16 waves/CU; ~2.2KB DMA in flight per
// wave -> read capacity >> HBM -> BW-bound at last.

#define PHB 8
#define PWB 32
#define CHB 4            // channels per item (per wave)
#define NROWS 5          // nh <= 5 (bsh <= 27/8)
#define WSTA 128         // padded staged width (two 64-col DMA halves)
#define BLK 128          // 2 waves = 2 independent items

typedef const void __attribute__((address_space(1)))* gas_ptr;
typedef void       __attribute__((address_space(3)))* las_ptr;

static __device__ __forceinline__ void gload4(const float* g, float* l) {
    // per-lane 4B global -> LDS (dest = wave-uniform base + lane*4)
    __builtin_amdgcn_global_load_lds((gas_ptr)(const void*)g,
                                     (las_ptr)(void*)l, 4, 0, 0);
}

__global__ __launch_bounds__(BLK) void ocr_roi_pool_kernel(
    const float* __restrict__ feats,
    const float* __restrict__ rois,
    float* __restrict__ out,
    int Cc, int Hc, int Wc)
{
#pragma clang fp contract(off)
    __shared__ float smax[2][CHB * NROWS * WSTA];   // 2 x 10 KB

    int t    = threadIdx.x;
    int wid  = t >> 6;                 // which item in this block
    int lane = t & 63;
    int pw   = lane & 31;
    int cs   = (lane >> 5) & 1;

    int item = blockIdx.x * 2 + wid;   // ((n*8 + ph)*32 + cg)
    int cg = item & 31;
    int ph = (item >> 5) & 7;
    int n  = item >> 8;
    int c0 = cg * CHB;

    // ---- ROI params: wave-uniform -> scalar (exact reference math) ----
    const float* r = rois + n * 5;
    int rb  = (int)r[0];
    int rsw = (int)floorf(r[1] * 0.25f + 0.5f);
    int rsh = (int)floorf(r[2] * 0.25f + 0.5f);
    int rew = (int)floorf(r[3] * 0.25f + 0.5f);
    int reh = (int)floorf(r[4] * 0.25f + 0.5f);

    int roi_w = max(rew - rsw + 1, 1);
    int roi_h = max(reh - rsh + 1, 1);
    int rpw   = (PHB * roi_w + roi_h - 1) / roi_h;

    float bsh = (float)roi_h / (float)PHB;
    float bsw = (float)roi_w / (float)rpw;

    // h-range for this ph (wave-uniform)
    int hs = (int)floorf((float)ph * bsh) + rsh;
    int he = (int)ceilf((float)(ph + 1) * bsh) + rsh;
    hs = min(max(hs, 0), Hc);
    he = min(max(he, 0), Hc);
    int nh = he - hs;                  // 0..5

    // staged w-window [wlo, whi): covers every non-pad bin's [ws,we)
    int wlo = min(max(rsw, 0), Wc);
    int whi = (int)ceilf((float)PWB * bsw) + rsw;
    whi = min(whi, rew + 4);
    whi = min(max(whi, 0), Wc);
    int wwid = whi - wlo;              // <= 108 < WSTA

    const int plane_stride = Hc * Wc;  // 32768
    float* S = smax[wid];

    // ---- DMA stage: raw rows -> LDS (per-lane 4B, exec-trimmed) ----
    if (nh > 0 && wwid > 0) {
        const float* pb = feats + (size_t)(rb * Cc + c0) * plane_stride;
        int  w64 = (wwid < 64) ? wwid : 64;
        bool a0  = lane < w64;
        bool a1  = lane < (wwid - 64);
        bool two = (wwid > 64);
        for (int rr = 0; rr < nh; ++rr) {          // wave-uniform trip
            int go = (hs + rr) * Wc + wlo + lane;
#pragma unroll
            for (int p = 0; p < CHB; ++p) {
                const float* g = pb + (size_t)p * plane_stride + go;
                float* l = S + (p * NROWS + rr) * WSTA;
                if (a0) gload4(g, l);              // cols 0..63
                if (two && a1) gload4(g + 64, l + 64);   // cols 64..wwid-1
            }
        }
    }
    // DMA completion before LDS reads (same wave; no cross-wave sharing)
    asm volatile("s_waitcnt vmcnt(0)" ::: "memory");

    // ---- per-lane bin bounds + fused max from LDS ----
    int ws = (int)floorf((float)pw * bsw) + rsw;
    int we = (int)ceilf((float)(pw + 1) * bsw) + rsw;
    ws = min(max(ws, 0), Wc);
    we = min(max(we, 0), Wc);

    bool zero = (ws >= rew) || (we <= ws) || (nh <= 0);
    int  nw   = we - ws;                       // 1..5 when valid
    int  base = min(ws - wlo, WSTA - 8);       // >=0; clamp keeps reads in-array
    base = max(base, 0);

    size_t ob = (((size_t)n * Cc + c0) * PHB + ph) * PWB + pw;
#pragma unroll
    for (int k = 0; k < 2; ++k) {
        int p = cs + 2 * k;                    // lane covers channels cs, cs+2
        const float* R0 = S + p * NROWS * WSTA + base;
        float m = -1e37f;
        for (int rr = 0; rr < nh; ++rr) {      // wave-uniform trip
            const float* row = R0 + rr * WSTA;
#pragma unroll
            for (int i = 0; i < 5; ++i) {      // 5 independent ds_reads,
                float v = row[i];              // masked beyond nw
                m = (i < nw) ? fmaxf(m, v) : m;
            }
        }
        out[ob + (size_t)p * (PHB * PWB)] = zero ? 0.0f : m;
    }
}

extern "C" void kernel_launch(void* const* d_in, const int* in_sizes, int n_in,
                              void* d_out, int out_size, void* d_ws, size_t ws_size,
                              hipStream_t stream) {
    const float* feats = (const float*)d_in[0];
    const float* rois  = (const float*)d_in[1];
    float* out = (float*)d_out;

    const int Cc = 128, Hc = 64, Wc = 512;
    int nroi  = in_sizes[1] / 5;
    int items = nroi * PHB * (Cc / CHB);   // 65536 items
    int blocks = items / 2;                // 32768 blocks x 2 waves

    ocr_roi_pool_kernel<<<blocks, BLK, 0, stream>>>(feats, rois, out, Cc, Hc, Wc);
}

// Round 15
// 28.479 us; speedup vs baseline: 1.9314x; 1.9314x over previous
//
#include <hip/hip_runtime.h>

// ROI max-pool (aspect-preserving "OCR" variant) — separable two-phase, v12.
// feats: (B=4, C=128, H=64, W=512) fp32
// rois:  (N, 5) fp32 = [batch, x1, y1, x2, y2] image coords, spatial scale 0.25
// out:   (N, C, PH=8, PW=32) fp32
//
// R10 structure (best: 25.8 us) with one change: phase-1 h-loop replaced by a
// fixed 5-row clamped full unroll (nh <= 5, wave-uniform; max is idempotent,
// clamped duplicate rows are L1 hits). All 4 channels x 5 rows = 20
// independent dwordx4 issued before any use -> ~320 B in flight per wave
// (R10's VGPR=24 showed only ~4-5 loads in flight = the 3.1 TB/s MLP cap).
// __launch_bounds__(64,4): 128-VGPR budget, 16 waves/CU.
// Phase 2: w-max from LDS, fixed 8-wide masked unroll (bin width <= 5).

#define PHB 8
#define PWB 32
#define CHB 8           // channels per block
#define WST 116         // staged width cap: ceil(32*bsw) <= 108, +3 align
#define BLK 64

static __device__ __forceinline__ float4 max4(float4 a, float4 b) {
    float4 r;
    r.x = fmaxf(a.x, b.x); r.y = fmaxf(a.y, b.y);
    r.z = fmaxf(a.z, b.z); r.w = fmaxf(a.w, b.w);
    return r;
}

__global__ __launch_bounds__(BLK, 4) void ocr_roi_pool_kernel(
    const float* __restrict__ feats,
    const float* __restrict__ rois,
    float* __restrict__ out,
    int Cc, int Hc, int Wc)
{
#pragma clang fp contract(off)
    __shared__ float smax[CHB * WST + 8];   // +8: phase-2 unroll over-read pad

    int b  = blockIdx.x;               // ((n*8 + ph)*16 + cg)
    int cg = b & 15;
    int ph = (b >> 4) & 7;
    int n  = b >> 7;
    int c0 = cg * CHB;

    // ---- ROI params: block-uniform -> scalar ----
    const float* r = rois + n * 5;
    int rb  = (int)r[0];
    int rsw = (int)floorf(r[1] * 0.25f + 0.5f);
    int rsh = (int)floorf(r[2] * 0.25f + 0.5f);
    int rew = (int)floorf(r[3] * 0.25f + 0.5f);
    int reh = (int)floorf(r[4] * 0.25f + 0.5f);

    int roi_w = max(rew - rsw + 1, 1);
    int roi_h = max(reh - rsh + 1, 1);
    int rpw   = (PHB * roi_w + roi_h - 1) / roi_h;

    float bsh = (float)roi_h / (float)PHB;
    float bsw = (float)roi_w / (float)rpw;

    // h-range for this ph (uniform over block), exact reference math
    int hs = (int)floorf((float)ph * bsh) + rsh;
    int he = (int)ceilf((float)(ph + 1) * bsh) + rsh;
    hs = min(max(hs, 0), Hc);
    he = min(max(he, 0), Hc);

    // staged w-window: covers every NON-PAD bin's reads; 4-aligned base.
    int wlo = min(max(rsw, 0), Wc);
    int whi = (int)ceilf((float)PWB * bsw) + rsw;
    whi = min(whi, rew + 4);
    whi = min(max(whi, 0), Wc);
    int wlo_al = wlo & ~3;
    int wwid = min(whi - wlo_al, WST);

    int t      = threadIdx.x;
    int lane_w = t & 31;
    int cslot  = t >> 5;               // 0..1
    int wp4    = lane_w * 4;           // this lane's 4-column slot

    const int plane_stride = Hc * Wc;  // 32768

    // ---- Phase 1: rowmax -> LDS (20 independent dwordx4, then max-tree) ----
    if (he > hs && wp4 < wwid) {
        const float* plane =
            feats + ((size_t)(rb * Cc + c0 + cslot) * Hc) * Wc;

        int o0 = hs * Wc + wlo_al + wp4;               // 16B-aligned, in-row
        int o1 = min(hs + 1, he - 1) * Wc + wlo_al + wp4;
        int o2 = min(hs + 2, he - 1) * Wc + wlo_al + wp4;
        int o3 = min(hs + 3, he - 1) * Wc + wlo_al + wp4;
        int o4 = min(hs + 4, he - 1) * Wc + wlo_al + wp4;

        float4 v0[4], v1[4], v2[4], v3[4], v4[4];
#pragma unroll
        for (int j = 0; j < 4; ++j) {
            const float* pj = plane + (size_t)(2 * j) * plane_stride;
            v0[j] = *reinterpret_cast<const float4*>(pj + o0);
            v1[j] = *reinterpret_cast<const float4*>(pj + o1);
            v2[j] = *reinterpret_cast<const float4*>(pj + o2);
            v3[j] = *reinterpret_cast<const float4*>(pj + o3);
            v4[j] = *reinterpret_cast<const float4*>(pj + o4);
        }
#pragma unroll
        for (int j = 0; j < 4; ++j) {
            float4 m01 = max4(v0[j], v1[j]);
            float4 m23 = max4(v2[j], v3[j]);
            float4 rm  = max4(max4(m01, m23), v4[j]);
            *reinterpret_cast<float4*>(&smax[(cslot + 2 * j) * WST + wp4]) = rm;
        }
    }
    __syncthreads();

    // ---- Phase 2: colmax from LDS (fixed 8-wide masked unroll), store ----
    int pw = lane_w;
    int ws = (int)floorf((float)pw * bsw) + rsw;
    int we = (int)ceilf((float)(pw + 1) * bsw) + rsw;
    ws = min(max(ws, 0), Wc);
    we = min(max(we, 0), Wc);

    bool pad   = (ws >= rew);
    bool empty = (he <= hs) || (we <= ws);

    size_t obase = (((size_t)n * Cc + c0 + cslot) * PHB + ph) * PWB + pw;
    if (pad || empty) {
#pragma unroll
        for (int j = 0; j < 4; ++j)
            out[obase + (size_t)(2 * j) * (PHB * PWB)] = 0.0f;
    } else {
        int base = ws - wlo_al;        // >= 0
        int nw   = we - ws;            // 1..5 (bsw <= 3.375)
#pragma unroll
        for (int j = 0; j < 4; ++j) {
            const float* row = &smax[(cslot + 2 * j) * WST + base];
            float m = -1e37f;
#pragma unroll
            for (int i = 0; i < 8; ++i) {        // 8 independent ds_reads,
                float v = row[i];                // masked beyond nw
                m = (i < nw) ? fmaxf(m, v) : m;
            }
            out[obase + (size_t)(2 * j) * (PHB * PWB)] = m;
        }
    }
}

extern "C" void kernel_launch(void* const* d_in, const int* in_sizes, int n_in,
                              void* d_out, int out_size, void* d_ws, size_t ws_size,
                              hipStream_t stream) {
    const float* feats = (const float*)d_in[0];
    const float* rois  = (const float*)d_in[1];
    float* out = (float*)d_out;

    const int Cc = 128, Hc = 64, Wc = 512;
    int nroi = in_sizes[1] / 5;
    int blocks = nroi * PHB * (Cc / CHB);   // 32768

    ocr_roi_pool_kernel<<<blocks, BLK, 0, stream>>>(feats, rois, out, Cc, Hc, Wc);
}

// Round 16
// 28.478 us; speedup vs baseline: 1.9316x; 1.0001x over previous
//
#include <hip/hip_runtime.h>

// ROI max-pool (aspect-preserving "OCR" variant) — separable two-phase, v13.
// feats: (B=4, C=128, H=64, W=512) fp32
// rois:  (N, 5) fp32 = [batch, x1, y1, x2, y2] image coords, spatial scale 0.25
// out:   (N, C, PH=8, PW=32) fp32
//
// R14 body (5-row clamped full unroll -> FETCH 81->43 MB, best L2 locality)
// with the launch_bounds min-waves cap REMOVED: R14's ",4" capped residency
// at 16 waves/CU while the compiler only used 32 VGPRs anyway — that cap was
// the whole 25.8->28.5 regression. VGPR=32 -> 32 single-wave blocks/CU.
// Phase 2: w-max from LDS, fixed 8-wide masked unroll (bin width <= 5).

#define PHB 8
#define PWB 32
#define CHB 8           // channels per block
#define WST 116         // staged width cap: ceil(32*bsw) <= 108, +3 align
#define BLK 64

static __device__ __forceinline__ float4 max4(float4 a, float4 b) {
    float4 r;
    r.x = fmaxf(a.x, b.x); r.y = fmaxf(a.y, b.y);
    r.z = fmaxf(a.z, b.z); r.w = fmaxf(a.w, b.w);
    return r;
}

__global__ __launch_bounds__(BLK) void ocr_roi_pool_kernel(
    const float* __restrict__ feats,
    const float* __restrict__ rois,
    float* __restrict__ out,
    int Cc, int Hc, int Wc)
{
#pragma clang fp contract(off)
    __shared__ float smax[CHB * WST + 8];   // +8: phase-2 unroll over-read pad

    int b  = blockIdx.x;               // ((n*8 + ph)*16 + cg)
    int cg = b & 15;
    int ph = (b >> 4) & 7;
    int n  = b >> 7;
    int c0 = cg * CHB;

    // ---- ROI params: block-uniform -> scalar ----
    const float* r = rois + n * 5;
    int rb  = (int)r[0];
    int rsw = (int)floorf(r[1] * 0.25f + 0.5f);
    int rsh = (int)floorf(r[2] * 0.25f + 0.5f);
    int rew = (int)floorf(r[3] * 0.25f + 0.5f);
    int reh = (int)floorf(r[4] * 0.25f + 0.5f);

    int roi_w = max(rew - rsw + 1, 1);
    int roi_h = max(reh - rsh + 1, 1);
    int rpw   = (PHB * roi_w + roi_h - 1) / roi_h;

    float bsh = (float)roi_h / (float)PHB;
    float bsw = (float)roi_w / (float)rpw;

    // h-range for this ph (uniform over block), exact reference math
    int hs = (int)floorf((float)ph * bsh) + rsh;
    int he = (int)ceilf((float)(ph + 1) * bsh) + rsh;
    hs = min(max(hs, 0), Hc);
    he = min(max(he, 0), Hc);

    // staged w-window: covers every NON-PAD bin's reads; 4-aligned base.
    int wlo = min(max(rsw, 0), Wc);
    int whi = (int)ceilf((float)PWB * bsw) + rsw;
    whi = min(whi, rew + 4);
    whi = min(max(whi, 0), Wc);
    int wlo_al = wlo & ~3;
    int wwid = min(whi - wlo_al, WST);

    int t      = threadIdx.x;
    int lane_w = t & 31;
    int cslot  = t >> 5;               // 0..1
    int wp4    = lane_w * 4;           // this lane's 4-column slot

    const int plane_stride = Hc * Wc;  // 32768

    // ---- Phase 1: rowmax -> LDS (5-row clamped unroll, max-tree) ----
    if (he > hs && wp4 < wwid) {
        const float* plane =
            feats + ((size_t)(rb * Cc + c0 + cslot) * Hc) * Wc;

        int o0 = hs * Wc + wlo_al + wp4;               // 16B-aligned, in-row
        int o1 = min(hs + 1, he - 1) * Wc + wlo_al + wp4;
        int o2 = min(hs + 2, he - 1) * Wc + wlo_al + wp4;
        int o3 = min(hs + 3, he - 1) * Wc + wlo_al + wp4;
        int o4 = min(hs + 4, he - 1) * Wc + wlo_al + wp4;

        float4 v0[4], v1[4], v2[4], v3[4], v4[4];
#pragma unroll
        for (int j = 0; j < 4; ++j) {
            const float* pj = plane + (size_t)(2 * j) * plane_stride;
            v0[j] = *reinterpret_cast<const float4*>(pj + o0);
            v1[j] = *reinterpret_cast<const float4*>(pj + o1);
            v2[j] = *reinterpret_cast<const float4*>(pj + o2);
            v3[j] = *reinterpret_cast<const float4*>(pj + o3);
            v4[j] = *reinterpret_cast<const float4*>(pj + o4);
        }
#pragma unroll
        for (int j = 0; j < 4; ++j) {
            float4 m01 = max4(v0[j], v1[j]);
            float4 m23 = max4(v2[j], v3[j]);
            float4 rm  = max4(max4(m01, m23), v4[j]);
            *reinterpret_cast<float4*>(&smax[(cslot + 2 * j) * WST + wp4]) = rm;
        }
    }
    __syncthreads();

    // ---- Phase 2: colmax from LDS (fixed 8-wide masked unroll), store ----
    int pw = lane_w;
    int ws = (int)floorf((float)pw * bsw) + rsw;
    int we = (int)ceilf((float)(pw + 1) * bsw) + rsw;
    ws = min(max(ws, 0), Wc);
    we = min(max(we, 0), Wc);

    bool pad   = (ws >= rew);
    bool empty = (he <= hs) || (we <= ws);

    size_t obase = (((size_t)n * Cc + c0 + cslot) * PHB + ph) * PWB + pw;
    if (pad || empty) {
#pragma unroll
        for (int j = 0; j < 4; ++j)
            out[obase + (size_t)(2 * j) * (PHB * PWB)] = 0.0f;
    } else {
        int base = ws - wlo_al;        // >= 0
        int nw   = we - ws;            // 1..5 (bsw <= 3.375)
#pragma unroll
        for (int j = 0; j < 4; ++j) {
            const float* row = &smax[(cslot + 2 * j) * WST + base];
            float m = -1e37f;
#pragma unroll
            for (int i = 0; i < 8; ++i) {        // 8 independent ds_reads,
                float v = row[i];                // masked beyond nw
                m = (i < nw) ? fmaxf(m, v) : m;
            }
            out[obase + (size_t)(2 * j) * (PHB * PWB)] = m;
        }
    }
}

extern "C" void kernel_launch(void* const* d_in, const int* in_sizes, int n_in,
                              void* d_out, int out_size, void* d_ws, size_t ws_size,
                              hipStream_t stream) {
    const float* feats = (const float*)d_in[0];
    const float* rois  = (const float*)d_in[1];
    float* out = (float*)d_out;

    const int Cc = 128, Hc = 64, Wc = 512;
    int nroi = in_sizes[1] / 5;
    int blocks = nroi * PHB * (Cc / CHB);   // 32768

    ocr_roi_pool_kernel<<<blocks, BLK, 0, stream>>>(feats, rois, out, Cc, Hc, Wc);
}

// Round 17
// 23.927 us; speedup vs baseline: 2.2989x; 1.1902x over previous
//
#include <hip/hip_runtime.h>

// ROI max-pool (aspect-preserving "OCR" variant) — separable two-phase, v14.
// feats: (B=4, C=128, H=64, W=512) fp32
// rois:  (N, 5) fp32 = [batch, x1, y1, x2, y2] image coords, spatial scale 0.25
// out:   (N, C, PH=8, PW=32) fp32
//
// R10/R15 hybrid: EXACT-nh staging. nh = he-hs is wave-uniform and <= 5, so a
// scalar 5-way branch picks a template body issuing exactly 4*nh independent
// dwordx4 (tight issue order like R15 -> 43 MB FETCH; no clamped-duplicate or
// dead loads -> ~45% less vmem issue work than the 5-row unroll; no loop
// overhead). Phase 2: w-max from LDS, 5-wide masked unroll (nw <= 5).
// 32768 single-wave blocks, VGPR ~32 -> 32 waves/CU.

#define PHB 8
#define PWB 32
#define CHB 8           // channels per block
#define WST 116         // staged width cap: ceil(32*bsw) <= 108, +3 align
#define BLK 64

static __device__ __forceinline__ float4 max4(float4 a, float4 b) {
    float4 r;
    r.x = fmaxf(a.x, b.x); r.y = fmaxf(a.y, b.y);
    r.z = fmaxf(a.z, b.z); r.w = fmaxf(a.w, b.w);
    return r;
}

template<int NH>
static __device__ __forceinline__ void stage_rows(
    const float* __restrict__ plane, int plane_stride, int Wc,
    int hs, int off, float* __restrict__ smax, int cslot)
{
    float4 v[NH][4];
#pragma unroll
    for (int rr = 0; rr < NH; ++rr) {
        int o = (hs + rr) * Wc + off;          // 16B-aligned, in-row
#pragma unroll
        for (int j = 0; j < 4; ++j)
            v[rr][j] = *reinterpret_cast<const float4*>(
                plane + (size_t)(2 * j) * plane_stride + o);
    }
#pragma unroll
    for (int j = 0; j < 4; ++j) {
        float4 rm = v[0][j];
#pragma unroll
        for (int rr = 1; rr < NH; ++rr) rm = max4(rm, v[rr][j]);
        *reinterpret_cast<float4*>(&smax[(cslot + 2 * j) * WST + off - (off & ~0x7fffffff)]) = rm;  // placeholder (unused)
    }
}

// NOTE: LDS write needs wp4, not off; specialized below instead.
template<int NH>
static __device__ __forceinline__ void stage_rows2(
    const float* __restrict__ plane, int plane_stride, int Wc,
    int hs, int goff, int wp4, float* __restrict__ smax, int cslot)
{
    float4 v[NH][4];
#pragma unroll
    for (int rr = 0; rr < NH; ++rr) {
        int o = (hs + rr) * Wc + goff;         // 16B-aligned, in-row
#pragma unroll
        for (int j = 0; j < 4; ++j)
            v[rr][j] = *reinterpret_cast<const float4*>(
                plane + (size_t)(2 * j) * plane_stride + o);
    }
#pragma unroll
    for (int j = 0; j < 4; ++j) {
        float4 rm = v[0][j];
#pragma unroll
        for (int rr = 1; rr < NH; ++rr) rm = max4(rm, v[rr][j]);
        *reinterpret_cast<float4*>(&smax[(cslot + 2 * j) * WST + wp4]) = rm;
    }
}

__global__ __launch_bounds__(BLK) void ocr_roi_pool_kernel(
    const float* __restrict__ feats,
    const float* __restrict__ rois,
    float* __restrict__ out,
    int Cc, int Hc, int Wc)
{
#pragma clang fp contract(off)
    __shared__ float smax[CHB * WST + 8];   // +8: phase-2 unroll over-read pad

    int b  = blockIdx.x;               // ((n*8 + ph)*16 + cg)
    int cg = b & 15;
    int ph = (b >> 4) & 7;
    int n  = b >> 7;
    int c0 = cg * CHB;

    // ---- ROI params: block-uniform -> scalar ----
    const float* r = rois + n * 5;
    int rb  = (int)r[0];
    int rsw = (int)floorf(r[1] * 0.25f + 0.5f);
    int rsh = (int)floorf(r[2] * 0.25f + 0.5f);
    int rew = (int)floorf(r[3] * 0.25f + 0.5f);
    int reh = (int)floorf(r[4] * 0.25f + 0.5f);

    int roi_w = max(rew - rsw + 1, 1);
    int roi_h = max(reh - rsh + 1, 1);
    int rpw   = (PHB * roi_w + roi_h - 1) / roi_h;

    float bsh = (float)roi_h / (float)PHB;
    float bsw = (float)roi_w / (float)rpw;

    // h-range for this ph (uniform over block), exact reference math
    int hs = (int)floorf((float)ph * bsh) + rsh;
    int he = (int)ceilf((float)(ph + 1) * bsh) + rsh;
    hs = min(max(hs, 0), Hc);
    he = min(max(he, 0), Hc);
    int nh = he - hs;                  // 0..5, wave-uniform

    // staged w-window: covers every NON-PAD bin's reads; 4-aligned base.
    int wlo = min(max(rsw, 0), Wc);
    int whi = (int)ceilf((float)PWB * bsw) + rsw;
    whi = min(whi, rew + 4);
    whi = min(max(whi, 0), Wc);
    int wlo_al = wlo & ~3;
    int wwid = min(whi - wlo_al, WST);

    int t      = threadIdx.x;
    int lane_w = t & 31;
    int cslot  = t >> 5;               // 0..1
    int wp4    = lane_w * 4;           // this lane's 4-column slot

    const int plane_stride = Hc * Wc;  // 32768

    // ---- Phase 1: rowmax -> LDS (exact-nh unroll, wave-uniform branch) ----
    if (nh > 0 && wp4 < wwid) {
        const float* plane =
            feats + ((size_t)(rb * Cc + c0 + cslot) * Hc) * Wc;
        int goff = wlo_al + wp4;
        switch (nh) {
        case 1: stage_rows2<1>(plane, plane_stride, Wc, hs, goff, wp4, smax, cslot); break;
        case 2: stage_rows2<2>(plane, plane_stride, Wc, hs, goff, wp4, smax, cslot); break;
        case 3: stage_rows2<3>(plane, plane_stride, Wc, hs, goff, wp4, smax, cslot); break;
        case 4: stage_rows2<4>(plane, plane_stride, Wc, hs, goff, wp4, smax, cslot); break;
        default: stage_rows2<5>(plane, plane_stride, Wc, hs, goff, wp4, smax, cslot); break;
        }
    }
    __syncthreads();

    // ---- Phase 2: colmax from LDS (fixed 5-wide masked unroll), store ----
    int pw = lane_w;
    int ws = (int)floorf((float)pw * bsw) + rsw;
    int we = (int)ceilf((float)(pw + 1) * bsw) + rsw;
    ws = min(max(ws, 0), Wc);
    we = min(max(we, 0), Wc);

    bool pad   = (ws >= rew);
    bool empty = (he <= hs) || (we <= ws);

    size_t obase = (((size_t)n * Cc + c0 + cslot) * PHB + ph) * PWB + pw;
    if (pad || empty) {
#pragma unroll
        for (int j = 0; j < 4; ++j)
            out[obase + (size_t)(2 * j) * (PHB * PWB)] = 0.0f;
    } else {
        int base = ws - wlo_al;        // >= 0
        int nw   = we - ws;            // 1..5 (bsw <= 3.375)
#pragma unroll
        for (int j = 0; j < 4; ++j) {
            const float* row = &smax[(cslot + 2 * j) * WST + base];
            float m = -1e37f;
#pragma unroll
            for (int i = 0; i < 5; ++i) {        // 5 independent ds_reads,
                float v = row[i];                // masked beyond nw
                m = (i < nw) ? fmaxf(m, v) : m;
            }
            out[obase + (size_t)(2 * j) * (PHB * PWB)] = m;
        }
    }
}

extern "C" void kernel_launch(void* const* d_in, const int* in_sizes, int n_in,
                              void* d_out, int out_size, void* d_ws, size_t ws_size,
                              hipStream_t stream) {
    const float* feats = (const float*)d_in[0];
    const float* rois  = (const float*)d_in[1];
    float* out = (float*)d_out;

    const int Cc = 128, Hc = 64, Wc = 512;
    int nroi = in_sizes[1] / 5;
    int blocks = nroi * PHB * (Cc / CHB);   // 32768

    ocr_roi_pool_kernel<<<blocks, BLK, 0, stream>>>(feats, rois, out, Cc, Hc, Wc);
}